// Round 1
// baseline (1162.985 us; speedup 1.0000x reference)
//
#include <hip/hip_runtime.h>

// VARImputer: B=256, S=2048, F=64, ORDER=5, K=ORDER*F=320.
// Sequential scan over S; parallel over B. One batch per block (256 blocks, 1/CU).
// 512 threads = 8 waves: wave q owns features [8q, 8q+8); lane = z*8+fo,
// z in [0,8) owns K-slice [40z, 40z+40) held in 10 float4 registers.
// Window = flat LDS buffer (5+CH)*64, rebased every CH=32 steps (no ring wrap
// => all inner-loop LDS addresses are base + static immediates).
// x/mask chunk prefetched into registers one chunk ahead, spilled to LDS at
// chunk boundary. One __syncthreads per step (frame publish).

#define BB  256
#define SS  2048
#define FF  64
#define ORD 5
#define KK  320
#define CH  32
#define NCH (SS / CH)   // 64
#define NQ  10          // 40 W-coeffs per thread as float4s

__global__ __launch_bounds__(512, 2)
void var_imputer_kernel(const float* __restrict__ x,
                        const int*   __restrict__ mask,
                        const float* __restrict__ W,
                        const float* __restrict__ bias,
                        float*       __restrict__ out)
{
    __shared__ __align__(16) float win[(ORD + CH) * FF];  // 2368 floats
    __shared__ __align__(16) float cx[CH * FF];           // 2048 floats
    __shared__ __align__(16) int   cm[CH * FF];           // 2048 ints
    __shared__ float p1s[32 * FF];                        // phase-1 sums
    __shared__ float p1c[32 * FF];                        // phase-1 counts

    const int b   = blockIdx.x;
    const int tid = threadIdx.x;
    const int wq  = tid >> 6;     // wave id -> feature group
    const int ln  = tid & 63;
    const int z   = ln >> 3;      // K-slice id
    const int fo  = ln & 7;
    const int f   = wq * 8 + fo;  // output feature owned by this thread

    const float* xb = x    + (size_t)b * SS * FF;
    const int*   mb = mask + (size_t)b * SS * FF;
    float*       ob = out  + (size_t)b * SS * FF;

    // ---- W slice into registers: W[f][40z + i], i in [0,40) ----
    float4 wr[NQ];
    {
        const float4* wp = (const float4*)(W + (size_t)f * KK + 40 * z);
        #pragma unroll
        for (int k = 0; k < NQ; ++k) wr[k] = wp[k];
    }
    const float breg = bias[f];

    // ---- prefetch chunk 0 (x, mask) into registers: 512 thr * 4 elems = CH*FF ----
    float4 crx = ((const float4*)xb)[tid];
    int4   crm = ((const int4*)mb)[tid];

    // ---- phase 1: per-feature mean over observed steps ----
    {
        const int f4 = tid & 15;   // feature quad
        const int sg = tid >> 4;   // s-group in [0,32)
        float a0 = 0.f, a1 = 0.f, a2 = 0.f, a3 = 0.f;
        float c0 = 0.f, c1 = 0.f, c2 = 0.f, c3 = 0.f;
        const float* xp = xb + (size_t)sg * FF + f4 * 4;
        const int*   mp = mb + (size_t)sg * FF + f4 * 4;
        for (int k = 0; k < SS / 32; ++k) {
            float4 xv = *(const float4*)(xp + (size_t)k * 32 * FF);
            int4   mv = *(const int4*)(mp + (size_t)k * 32 * FF);
            float m0 = (float)mv.x, m1 = (float)mv.y;
            float m2 = (float)mv.z, m3 = (float)mv.w;
            a0 = fmaf(xv.x, m0, a0); a1 = fmaf(xv.y, m1, a1);
            a2 = fmaf(xv.z, m2, a2); a3 = fmaf(xv.w, m3, a3);
            c0 += m0; c1 += m1; c2 += m2; c3 += m3;
        }
        const int bi = sg * FF + f4 * 4;
        p1s[bi + 0] = a0; p1s[bi + 1] = a1; p1s[bi + 2] = a2; p1s[bi + 3] = a3;
        p1c[bi + 0] = c0; p1c[bi + 1] = c1; p1c[bi + 2] = c2; p1c[bi + 3] = c3;
        __syncthreads();
        if (tid < FF) {
            float sm = 0.f, ct = 0.f;
            #pragma unroll 4
            for (int g = 0; g < 32; ++g) {
                sm += p1s[g * FF + tid];
                ct += p1c[g * FF + tid];
            }
            const float mean = sm / (ct + 1e-8f);
            #pragma unroll
            for (int l = 0; l < ORD; ++l) win[l * FF + tid] = mean;
        }
    }
    // (visibility of mean-writes to win is covered by the boundary barrier below)

    // ---- main scan ----
    const float* wbase = &win[40 * z];
    for (int c = 0; c < NCH; ++c) {
        // chunk boundary: rebase window tail, publish prefetched chunk
        if (c > 0 && tid < KK) win[tid] = win[CH * FF + tid];  // last 5 frames -> front
        ((float4*)cx)[tid] = crx;
        ((int4*)cm)[tid]   = crm;
        __syncthreads();
        if (c + 1 < NCH) {  // issue next chunk's loads; first use is next boundary
            crx = ((const float4*)(xb + (size_t)(c + 1) * CH * FF))[tid];
            crm = ((const int4*)(mb + (size_t)(c + 1) * CH * FF))[tid];
        }

        for (int srel = 0; srel < CH; ++srel) {
            const float* wp = wbase + srel * FF;
            float p0 = 0.f, p1 = 0.f, p2 = 0.f, p3 = 0.f;
            #pragma unroll
            for (int k = 0; k < NQ; ++k) {
                const float4 wv = *(const float4*)(wp + 4 * k);
                p0 = fmaf(wv.x, wr[k].x, p0);
                p1 = fmaf(wv.y, wr[k].y, p1);
                p2 = fmaf(wv.z, wr[k].z, p2);
                p3 = fmaf(wv.w, wr[k].w, p3);
            }
            float p = (p0 + p1) + (p2 + p3);
            p += __shfl_xor(p, 8);
            p += __shfl_xor(p, 16);
            p += __shfl_xor(p, 32);
            if (z == 0) {
                const int idx = srel * FF + f;
                const float nv = cm[idx] ? cx[idx] : (p + breg);
                win[(ORD + srel) * FF + f] = nv;        // publish frame s
                ob[(size_t)c * CH * FF + idx] = nv;     // store output
            }
            __syncthreads();  // frame s visible before step s+1 reads window
        }
    }
}

extern "C" void kernel_launch(void* const* d_in, const int* in_sizes, int n_in,
                              void* d_out, int out_size, void* d_ws, size_t ws_size,
                              hipStream_t stream)
{
    const float* x    = (const float*)d_in[0];
    const int*   mask = (const int*)d_in[1];
    const float* W    = (const float*)d_in[2];
    const float* bias = (const float*)d_in[3];
    float*       out  = (float*)d_out;

    var_imputer_kernel<<<dim3(BB), dim3(512), 0, stream>>>(x, mask, W, bias, out);
}

// Round 2
// 1075.128 us; speedup vs baseline: 1.0817x; 1.0817x over previous
//
#include <hip/hip_runtime.h>

// VARImputer: B=256, S=2048, F=64, ORDER=5, K=320. One batch per block/CU.
// 512 threads = 8 waves: wave wq owns features [8wq,8wq+8); lane = z*8+fo,
// z in [0,8) owns K-subslice [8z,8z+8) *of each of the 5 W blocks*.
//
// Pending-accumulator restructure: when frame s-1 is published, thread (f,z)
// loads its 8 floats of that frame ONCE (2 x b128) and applies all 5 W blocks:
//   block4 -> critical (target s, seeded with pending p1, 3-shuffle reduce)
//   block3..0 -> pending p1..p4 for targets s+1..s+4 (off critical path)
// Outputs accumulate in the LDS window rows; stored as coalesced float4 once
// per 32-step chunk (no per-step global store).

#define BB  256
#define SS  2048
#define FF  64
#define ORD 5
#define KK  320
#define CH  32
#define NCH (SS / CH)   // 64

__device__ __forceinline__ float dot8(const float4 w0, const float4 w1,
                                      const float4 a, const float4 b) {
    float s0 = w0.x * a.x;
    s0 = fmaf(w0.y, a.y, s0);
    s0 = fmaf(w0.z, a.z, s0);
    s0 = fmaf(w0.w, a.w, s0);
    float s1 = w1.x * b.x;
    s1 = fmaf(w1.y, b.y, s1);
    s1 = fmaf(w1.z, b.z, s1);
    s1 = fmaf(w1.w, b.w, s1);
    return s0 + s1;
}

__global__ __launch_bounds__(512, 2)
void var_imputer_kernel(const float* __restrict__ x,
                        const int*   __restrict__ mask,
                        const float* __restrict__ W,
                        const float* __restrict__ bias,
                        float*       __restrict__ out)
{
    __shared__ __align__(16) float win[(ORD + CH) * FF];  // 2368 floats
    __shared__ __align__(16) float cx[CH * FF];
    __shared__ __align__(16) int   cm[CH * FF];
    __shared__ float p1s[32 * FF];
    __shared__ float p1c[32 * FF];

    const int b   = blockIdx.x;
    const int tid = threadIdx.x;
    const int wq  = tid >> 6;
    const int ln  = tid & 63;
    const int z   = ln >> 3;
    const int fo  = ln & 7;
    const int f   = wq * 8 + fo;

    const float* xb = x    + (size_t)b * SS * FF;
    const int*   mb = mask + (size_t)b * SS * FF;
    float*       ob = out  + (size_t)b * SS * FF;

    // ---- W into registers: wr[blk] covers W[f][blk*64 + 8z .. +8) ----
    float4 wr[5][2];
    #pragma unroll
    for (int bk = 0; bk < 5; ++bk) {
        const float4* wp = (const float4*)(W + (size_t)f * KK + bk * 64 + 8 * z);
        wr[bk][0] = wp[0];
        wr[bk][1] = wp[1];
    }
    const float breg = bias[f];

    // ---- prefetch chunk 0 ----
    float4 crx = ((const float4*)xb)[tid];
    int4   crm = ((const int4*)mb)[tid];

    // ---- phase 1: per-feature mean ----
    {
        const int f4 = tid & 15;
        const int sg = tid >> 4;
        float a0 = 0.f, a1 = 0.f, a2 = 0.f, a3 = 0.f;
        float c0 = 0.f, c1 = 0.f, c2 = 0.f, c3 = 0.f;
        const float* xp = xb + (size_t)sg * FF + f4 * 4;
        const int*   mp = mb + (size_t)sg * FF + f4 * 4;
        for (int k = 0; k < SS / 32; ++k) {
            float4 xv = *(const float4*)(xp + (size_t)k * 32 * FF);
            int4   mv = *(const int4*)(mp + (size_t)k * 32 * FF);
            float m0 = (float)mv.x, m1 = (float)mv.y;
            float m2 = (float)mv.z, m3 = (float)mv.w;
            a0 = fmaf(xv.x, m0, a0); a1 = fmaf(xv.y, m1, a1);
            a2 = fmaf(xv.z, m2, a2); a3 = fmaf(xv.w, m3, a3);
            c0 += m0; c1 += m1; c2 += m2; c3 += m3;
        }
        const int bi = sg * FF + f4 * 4;
        p1s[bi + 0] = a0; p1s[bi + 1] = a1; p1s[bi + 2] = a2; p1s[bi + 3] = a3;
        p1c[bi + 0] = c0; p1c[bi + 1] = c1; p1c[bi + 2] = c2; p1c[bi + 3] = c3;
        __syncthreads();
        if (tid < FF) {
            float sm = 0.f, ct = 0.f;
            #pragma unroll 4
            for (int g = 0; g < 32; ++g) {
                sm += p1s[g * FF + tid];
                ct += p1c[g * FF + tid];
            }
            const float mean = sm / (ct + 1e-8f);
            #pragma unroll
            for (int l = 0; l < ORD; ++l) win[l * FF + tid] = mean;
        }
    }
    __syncthreads();  // mean rows visible for warm-up reads

    // ---- warm-up: pending partials from pad frames (all == mean) ----
    float p1, p2, p3, p4;
    {
        const float4* mp = (const float4*)(&win[8 * z]);  // row 0 slice
        const float4 ma = mp[0], mb4 = mp[1];
        const float S0 = dot8(wr[0][0], wr[0][1], ma, mb4);
        const float S1 = dot8(wr[1][0], wr[1][1], ma, mb4);
        const float S2 = dot8(wr[2][0], wr[2][1], ma, mb4);
        const float S3 = dot8(wr[3][0], wr[3][1], ma, mb4);
        p1 = S0 + S1 + S2 + S3;   // P[0]: frames -5..-2, blocks 0..3
        p2 = S0 + S1 + S2;        // P[1] entry (missing frame -1 blk3)
        p3 = S0 + S1;             // P[2] entry
        p4 = S0;                  // P[3] entry
    }

    // ---- main scan ----
    for (int c = 0; c < NCH; ++c) {
        if (c > 0) {
            // rebase window tail: rows 32..36 -> rows 0..4
            if (tid < KK) win[tid] = win[CH * FF + tid];
            // store chunk c-1 outputs (rows 5..36), coalesced float4
            const float4 ov = ((const float4*)&win[ORD * FF])[tid];
            ((float4*)(ob + (size_t)(c - 1) * CH * FF))[tid] = ov;
        }
        ((float4*)cx)[tid] = crx;
        ((int4*)cm)[tid]   = crm;
        __syncthreads();
        if (c + 1 < NCH) {
            crx = ((const float4*)(xb + (size_t)(c + 1) * CH * FF))[tid];
            crm = ((const int4*)(mb + (size_t)(c + 1) * CH * FF))[tid];
        }

        for (int srel = 0; srel < CH; ++srel) {
            // frame s-1 slice: 8 floats, the ONLY per-step LDS data needed
            const float* frp = &win[(ORD + srel - 1) * FF + 8 * z];
            const float4 fa = ((const float4*)frp)[0];
            const float4 fb = ((const float4*)frp)[1];
            // observed x / mask for this (srel, f) — independent of fr chain
            const int   idx   = srel * FF + f;
            const int   mflag = cm[idx];
            const float xval  = cx[idx];

            // critical: block4 dot seeded with pending p1, then butterfly
            float ta = fmaf(wr[4][0].x, fa.x, p1);
            ta = fmaf(wr[4][0].y, fa.y, ta);
            ta = fmaf(wr[4][0].z, fa.z, ta);
            ta = fmaf(wr[4][0].w, fa.w, ta);
            float tb = wr[4][1].x * fb.x;
            tb = fmaf(wr[4][1].y, fb.y, tb);
            tb = fmaf(wr[4][1].z, fb.z, tb);
            tb = fmaf(wr[4][1].w, fb.w, tb);
            float t = ta + tb;
            t += __shfl_xor(t, 8);
            t += __shfl_xor(t, 16);
            t += __shfl_xor(t, 32);

            const float nv = mflag ? xval : (t + breg);
            if (z == 0) win[(ORD + srel) * FF + f] = nv;  // publish frame s

            // pending updates (off critical path, reuse fa/fb)
            const float q1 = p2 + dot8(wr[3][0], wr[3][1], fa, fb);
            const float q2 = p3 + dot8(wr[2][0], wr[2][1], fa, fb);
            const float q3 = p4 + dot8(wr[1][0], wr[1][1], fa, fb);
            const float q4 =      dot8(wr[0][0], wr[0][1], fa, fb);
            p1 = q1; p2 = q2; p3 = q3; p4 = q4;

            __syncthreads();  // frame s visible before step s+1
        }
    }

    // final chunk output store (last step ended with __syncthreads)
    {
        const float4 ov = ((const float4*)&win[ORD * FF])[tid];
        ((float4*)(ob + (size_t)(NCH - 1) * CH * FF))[tid] = ov;
    }
}

extern "C" void kernel_launch(void* const* d_in, const int* in_sizes, int n_in,
                              void* d_out, int out_size, void* d_ws, size_t ws_size,
                              hipStream_t stream)
{
    const float* x    = (const float*)d_in[0];
    const int*   mask = (const int*)d_in[1];
    const float* W    = (const float*)d_in[2];
    const float* bias = (const float*)d_in[3];
    float*       out  = (float*)d_out;

    var_imputer_kernel<<<dim3(BB), dim3(512), 0, stream>>>(x, mask, W, bias, out);
}